// Round 1
// baseline (643.400 us; speedup 1.0000x reference)
//
#include <hip/hip_runtime.h>

#define CIN   8
#define COUT  16
#define HH    56
#define WW    56
#define SS    784                  // 28*28 symbolic vector per pixel
#define PLANE (HH * WW * SS)       // 2458624 floats per channel plane
#define ROW   (WW * SS)            // 43904
#define NF4   (HH * WW * (SS / 4)) // 614656 float4 units = 2401 * 256
#define SYM_OUT_SZ (COUT * PLANE)  // 39337984

// Main symbolic-bound conv.
// Identity: with s=lv+uv, d=lv-uv:
//   lx_out = sum w*lv [w>0] + w*uv [w<0] = 0.5*(sum w*s + sum |w|*d)
//   ux_out =                             = 0.5*(sum w*s - sum |w|*d)
// One thread owns one float4 of the 784-vector; 16 cout accumulated in regs.
__global__ __launch_bounds__(256) void ibp_conv_sym(
    const float* __restrict__ lx, const float* __restrict__ ux,
    const float* __restrict__ wgt,
    float* __restrict__ lx_out, float* __restrict__ ux_out)
{
    __shared__ float2 wsh[72][COUT];   // (0.5*w, 0.5*|w|) per (tap, cout)
    const int tid = threadIdx.x;
    for (int i = tid; i < 72 * COUT; i += 256) {
        int tap = i >> 4, co = i & 15;
        int ci = tap / 9, r = tap - ci * 9;
        int dh = r / 3, dw = r - dh * 3;
        float w = wgt[((co * CIN + ci) * 3 + dh) * 3 + dw];
        wsh[tap][co] = make_float2(0.5f * w, 0.5f * fabsf(w));
    }
    __syncthreads();

    const int gi  = blockIdx.x * 256 + tid;   // float4 index in (h,w,s4) space
    const int pix = gi / 196;                 // = h*56 + w   (196 = 784/4)
    const int j4  = gi - pix * 196;
    const int h   = pix / WW;
    const int w   = pix - h * WW;
    (void)j4;

    const float* bl0 = lx + (size_t)gi * 4;
    const float* bu0 = ux + (size_t)gi * 4;

    float4 A[COUT], B[COUT];
    #pragma unroll
    for (int co = 0; co < COUT; ++co) {
        A[co] = make_float4(0.f, 0.f, 0.f, 0.f);
        B[co] = make_float4(0.f, 0.f, 0.f, 0.f);
    }

    for (int ci = 0; ci < CIN; ++ci) {
        const float* bl = bl0 + ci * PLANE;
        const float* bu = bu0 + ci * PLANE;
        #pragma unroll
        for (int dh = 0; dh < 3; ++dh) {
            const int ih = h + dh - 1;
            const bool vh = (unsigned)ih < (unsigned)HH;
            #pragma unroll
            for (int dw = 0; dw < 3; ++dw) {
                const int iw = w + dw - 1;
                const bool ok = vh && ((unsigned)iw < (unsigned)WW);
                const int off = (dh - 1) * ROW + (dw - 1) * SS;
                float4 lv = make_float4(0.f, 0.f, 0.f, 0.f);
                float4 uv = make_float4(0.f, 0.f, 0.f, 0.f);
                if (ok) {
                    lv = *(const float4*)(bl + off);
                    uv = *(const float4*)(bu + off);
                }
                const float sx = lv.x + uv.x, sy = lv.y + uv.y,
                            sz = lv.z + uv.z, sw = lv.w + uv.w;
                const float dx = lv.x - uv.x, dy = lv.y - uv.y,
                            dz = lv.z - uv.z, dwv = lv.w - uv.w;
                const int tap = ci * 9 + dh * 3 + dw;
                #pragma unroll
                for (int co = 0; co < COUT; ++co) {
                    const float2 wp = wsh[tap][co];
                    A[co].x += wp.x * sx;  A[co].y += wp.x * sy;
                    A[co].z += wp.x * sz;  A[co].w += wp.x * sw;
                    B[co].x += wp.y * dx;  B[co].y += wp.y * dy;
                    B[co].z += wp.y * dz;  B[co].w += wp.y * dwv;
                }
            }
        }
    }

    #pragma unroll
    for (int co = 0; co < COUT; ++co) {
        float4 lo, uo;
        lo.x = A[co].x + B[co].x;  uo.x = A[co].x - B[co].x;
        lo.y = A[co].y + B[co].y;  uo.y = A[co].y - B[co].y;
        lo.z = A[co].z + B[co].z;  uo.z = A[co].z - B[co].z;
        lo.w = A[co].w + B[co].w;  uo.w = A[co].w - B[co].w;
        *(float4*)(lx_out + (size_t)co * PLANE + (size_t)gi * 4) = lo;
        *(float4*)(ux_out + (size_t)co * PLANE + (size_t)gi * 4) = uo;
    }
}

// Constant-offset conv (tiny: 16*56*56 outputs each).
__global__ __launch_bounds__(256) void ibp_conv_const(
    const float* __restrict__ lc, const float* __restrict__ uc,
    const float* __restrict__ wgt, const float* __restrict__ bias,
    float* __restrict__ lc_out, float* __restrict__ uc_out)
{
    const int idx = blockIdx.x * 256 + threadIdx.x;
    if (idx >= COUT * HH * WW) return;
    const int co  = idx / (HH * WW);
    const int pix = idx - co * (HH * WW);
    const int h = pix / WW, w = pix - (pix / WW) * WW;

    float Aa = 0.f, Bb = 0.f;
    for (int ci = 0; ci < CIN; ++ci) {
        #pragma unroll
        for (int dh = 0; dh < 3; ++dh) {
            const int ih = h + dh - 1;
            if ((unsigned)ih >= (unsigned)HH) continue;
            #pragma unroll
            for (int dw = 0; dw < 3; ++dw) {
                const int iw = w + dw - 1;
                if ((unsigned)iw >= (unsigned)WW) continue;
                const float l = lc[(ci * HH + ih) * WW + iw];
                const float u = uc[(ci * HH + ih) * WW + iw];
                const float wv = wgt[((co * CIN + ci) * 3 + dh) * 3 + dw];
                Aa += wv * (l + u);
                Bb += fabsf(wv) * (l - u);
            }
        }
    }
    const float b = bias[co];
    lc_out[idx] = 0.5f * (Aa + Bb) + b;
    uc_out[idx] = 0.5f * (Aa - Bb) + b;
}

extern "C" void kernel_launch(void* const* d_in, const int* in_sizes, int n_in,
                              void* d_out, int out_size, void* d_ws, size_t ws_size,
                              hipStream_t stream) {
    const float* lx   = (const float*)d_in[0];
    const float* ux   = (const float*)d_in[1];
    const float* lc   = (const float*)d_in[2];
    const float* uc   = (const float*)d_in[3];
    const float* wgt  = (const float*)d_in[4];
    const float* bias = (const float*)d_in[5];

    float* out    = (float*)d_out;
    float* lx_out = out;
    float* ux_out = out + (size_t)SYM_OUT_SZ;
    float* lc_out = out + (size_t)2 * SYM_OUT_SZ;
    float* uc_out = lc_out + COUT * HH * WW;

    ibp_conv_sym<<<NF4 / 256, 256, 0, stream>>>(lx, ux, wgt, lx_out, ux_out);

    const int nconst = COUT * HH * WW;
    ibp_conv_const<<<(nconst + 255) / 256, 256, 0, stream>>>(
        lc, uc, wgt, bias, lc_out, uc_out);
}